// Round 13
// baseline (352.948 us; speedup 1.0000x reference)
//
#include <hip/hip_runtime.h>
#include <hip/hip_bf16.h>
#include <stdint.h>
#include <stddef.h>

typedef __hip_bfloat16 bf16;
typedef __attribute__((ext_vector_type(8))) short bhalf8;
typedef __attribute__((ext_vector_type(4))) short short4v;
typedef __attribute__((ext_vector_type(4))) float floatx4;

static __device__ __forceinline__ float b2f(bf16 v) { return __bfloat162float(v); }
static __device__ __forceinline__ bf16  f2b(float v) { return __float2bfloat16(v); }
static __device__ __forceinline__ short f2s(float v) {
    union { bf16 b; short s; } u; u.b = __float2bfloat16(v); return u.s;
}
static __device__ __forceinline__ float s2f(short v) {
    union { short s; bf16 b; } u; u.s = v; return b2f(u.b);
}

// dtype-agnostic scalar load: flag==1 -> fp32 data, flag==0 -> bf16 data
static __device__ __forceinline__ float loadf(const void* p, size_t i, int f32) {
    return f32 ? ((const float*)p)[i] : b2f(((const bf16*)p)[i]);
}

// async global->LDS, 16B per lane. LDS dest must be wave-uniform base + lane*16.
static __device__ __forceinline__ void gl_lds16(const void* g, void* l) {
    __builtin_amdgcn_global_load_lds(
        (const __attribute__((address_space(1))) void*)g,
        (__attribute__((address_space(3))) void*)l, 16, 0, 0);
}

// load 4 consecutive bf16 mask values (8B) at 4-aligned element index
static __device__ __forceinline__ void load_mask4b(const bf16* m, size_t idx,
                                                   float* mv) {
    short4v v = *(const short4v*)(m + idx);
    #pragma unroll
    for (int t = 0; t < 4; t++) mv[t] = s2f(v[t]);
}

// -------------------------------------------------------------------------
// Fused prep (unchanged R12): inline dtype-detect + [cvt feat | cvt mask |
// zero accum | transpose W1 | transpose skip1 | wproj2 | wproj1].
__global__ __launch_bounds__(256) void prep_k(const void* __restrict__ feat,
                                              bf16* __restrict__ featc,
                                              const void* __restrict__ mask,
                                              bf16* __restrict__ maskb,
                                              float* __restrict__ zbase, int nzero,
                                              const void* __restrict__ W1,
                                              bf16* __restrict__ W1t,
                                              const void* __restrict__ skip1,
                                              bf16* __restrict__ S1t,
                                              const void* __restrict__ W2,
                                              const void* __restrict__ a_src1,
                                              const void* __restrict__ a_tgt1,
                                              const void* __restrict__ a_src2,
                                              const void* __restrict__ a_tgt2,
                                              bf16* __restrict__ Wa1b,
                                              bf16* __restrict__ Wa2b,
                                              int* __restrict__ flagp)
{
    __shared__ int sflag;
    __shared__ bf16 tile[32][33];
    const int tid = threadIdx.x;

    if (tid < 64) {
        const unsigned short* s = (const unsigned short*)W1;
        int bad = 0;
        #pragma unroll
        for (int i = 0; i < 4; i++) {
            int e = (s[tid * 4 + i] >> 7) & 0xFF;
            if (e > 0x85 || (e != 0 && e < 0x60)) bad++;
        }
        bad += __shfl_xor(bad, 1, 64);
        bad += __shfl_xor(bad, 2, 64);
        bad += __shfl_xor(bad, 4, 64);
        bad += __shfl_xor(bad, 8, 64);
        bad += __shfl_xor(bad, 16, 64);
        bad += __shfl_xor(bad, 32, 64);
        if (tid == 0) sflag = (bad > 16) ? 1 : 0;
    }
    __syncthreads();
    const int f32 = sflag;

    int id = blockIdx.x;
    if (id == 0 && tid == 0) *flagp = f32;

    if (id < 4096) {                           // ---- cvt feat -> bf16 ----
        const int i = id * 256 + tid;
        featc[i] = f32 ? f2b(((const float*)feat)[i]) : ((const bf16*)feat)[i];
        return;
    }
    id -= 4096;
    if (id < 4096) {                           // ---- cvt mask -> bf16 ----
        const size_t i = (size_t)id * 1024 + tid * 4;
        if (f32) {
            float4 v = *(const float4*)((const float*)mask + i);
            short4v o;
            o[0] = f2s(v.x); o[1] = f2s(v.y); o[2] = f2s(v.z); o[3] = f2s(v.w);
            *(short4v*)(maskb + i) = o;
        } else {
            *(short4v*)(maskb + i) = *(const short4v*)((const bf16*)mask + i);
        }
        return;
    }
    id -= 4096;
    if (id < 480) {                            // ---- zero accumulators ----
        const int i = id * 256 + tid;
        if (i < nzero) zbase[i] = 0.f;
        return;
    }
    id -= 480;
    if (id < 1024) {                           // ---- transposes (256x2048) ----
        const void* in = (id < 512) ? W1 : skip1;
        bf16* out = (id < 512) ? W1t : S1t;
        const int t = id & 511;
        const int bx = t & 63, byy = t >> 6;
        const int tx = tid & 31, ty = tid >> 5;
        const int c0 = bx * 32, r0 = byy * 32;
        #pragma unroll
        for (int yy = ty; yy < 32; yy += 8)
            tile[yy][tx] = f2b(loadf(in, (size_t)(r0 + yy) * 2048 + c0 + tx, f32));
        __syncthreads();
        #pragma unroll
        for (int yy = ty; yy < 32; yy += 8)
            out[(size_t)(c0 + yy) * 256 + r0 + tx] = tile[tx][yy];
        return;
    }
    id -= 1024;
    if (id < 512) {
        // ---- wproj2 ----
        const int wave = tid >> 6, lane = tid & 63;
        const int base = id * 64;
        const int hh = base >> 11, h = hh & 7;
        const void* a = (hh < 8) ? a_src2 : a_tgt2;
        float av[4];
        #pragma unroll
        for (int i = 0; i < 4; i++) av[i] = loadf(a, h * 256 + lane * 4 + i, f32);
        #pragma unroll 4
        for (int o = 0; o < 16; o++) {
            const int idx = base + wave * 16 + o;
            const int k = idx & 2047;
            float acc = 0.f;
            #pragma unroll
            for (int i = 0; i < 4; i++)
                acc = fmaf(loadf(W2, (size_t)k * 2048 + h * 256 + lane * 4 + i, f32),
                           av[i], acc);
            #pragma unroll
            for (int off2 = 32; off2; off2 >>= 1) acc += __shfl_down(acc, off2, 64);
            if (lane == 0) Wa2b[idx] = f2b(acc);
        }
        return;
    }
    id -= 512;
    // ---- wproj1 ----
    {
        const int wave = tid >> 6, lane = tid & 63;
        const int base = id * 64;
        const int hh = base >> 8, h = hh & 7;
        const void* a = (hh < 8) ? a_src1 : a_tgt1;
        float av[4];
        #pragma unroll
        for (int i = 0; i < 4; i++) av[i] = loadf(a, h * 256 + lane * 4 + i, f32);
        #pragma unroll 4
        for (int o = 0; o < 16; o++) {
            const int idx = base + wave * 16 + o;
            const int k = idx & 255;
            float acc = 0.f;
            #pragma unroll
            for (int i = 0; i < 4; i++)
                acc = fmaf(loadf(W1, (size_t)k * 2048 + h * 256 + lane * 4 + i, f32),
                           av[i], acc);
            #pragma unroll
            for (int off2 = 32; off2; off2 >>= 1) acc += __shfl_down(acc, off2, 64);
            if (lane == 0) Wa1b[idx] = f2b(acc);
        }
    }
}

// -------------------------------------------------------------------------
// Dual GEMM, K=256, m97 structure, grid (32,16,2) (unchanged).
__global__ __launch_bounds__(256) void gemm_dual(const bf16* __restrict__ featc,
                                                 const bf16* __restrict__ W1t,
                                                 const bf16* __restrict__ S1t,
                                                 bf16* __restrict__ pT,
                                                 bf16* __restrict__ sk1)
{
    __shared__ __align__(16) short sA[128][32];
    __shared__ __align__(16) short sB[128][32];
    const int tid = threadIdx.x;
    const int z = blockIdx.z;
    const bf16* A  = z ? featc : W1t;
    const bf16* Bt = z ? S1t   : featc;
    const int mbase = (z ? blockIdx.x : blockIdx.y) * 128;
    const int nbase = (z ? blockIdx.y : blockIdx.x) * 128;
    const int wave = tid >> 6, lane = tid & 63;
    const int wm = wave >> 1, wn = wave & 1;
    const int lrow = lane & 15, quad = lane >> 4;

    floatx4 acc[4][4];
    #pragma unroll
    for (int i = 0; i < 4; i++)
        #pragma unroll
        for (int j = 0; j < 4; j++)
            acc[i][j] = (floatx4){0.f, 0.f, 0.f, 0.f};

    const int srow = wave * 32 + (lane >> 2);
    const int scol = (lane & 3) * 8;
    const bf16* gA0 = A  + (size_t)(mbase + srow) * 256 + scol;
    const bf16* gA1 = gA0 + (size_t)16 * 256;
    const bf16* gB0 = Bt + (size_t)(nbase + srow) * 256 + scol;
    const bf16* gB1 = gB0 + (size_t)16 * 256;
    char* lA0 = (char*)&sA[0][0] + wave * 2048 + lane * 16;
    char* lA1 = lA0 + 1024;
    char* lB0 = (char*)&sB[0][0] + wave * 2048 + lane * 16;
    char* lB1 = lB0 + 1024;

    for (int k0 = 0; k0 < 256; k0 += 32) {
        __syncthreads();
        gl_lds16(gA0 + k0, lA0);
        gl_lds16(gA1 + k0, lA1);
        gl_lds16(gB0 + k0, lB0);
        gl_lds16(gB1 + k0, lB1);
        __syncthreads();
        bhalf8 af[4], bfr[4];
        #pragma unroll
        for (int t = 0; t < 4; t++) af[t]  = *(const bhalf8*)&sA[wm * 64 + t * 16 + lrow][quad * 8];
        #pragma unroll
        for (int t = 0; t < 4; t++) bfr[t] = *(const bhalf8*)&sB[wn * 64 + t * 16 + lrow][quad * 8];
        #pragma unroll
        for (int tm = 0; tm < 4; tm++)
            #pragma unroll
            for (int tn = 0; tn < 4; tn++)
                acc[tm][tn] = __builtin_amdgcn_mfma_f32_16x16x32_bf16(af[tm], bfr[tn], acc[tm][tn], 0, 0, 0);
    }

    #pragma unroll
    for (int tm = 0; tm < 4; tm++) {
        #pragma unroll
        for (int tn = 0; tn < 4; tn++) {
            const int col = nbase + wn * 64 + tn * 16 + lrow;
            #pragma unroll
            for (int r = 0; r < 4; r++) {
                const int row = mbase + wm * 64 + tm * 16 + quad * 4 + r;
                if (z) {
                    sk1[(size_t)row * 2048 + col] = f2b(acc[tm][tn][r]);
                } else {
                    const size_t idx = ((size_t)((col >> 10) * 8 + (row >> 8)) << 18)
                                     + (size_t)(row & 255) * 1024 + (col & 1023);
                    pT[idx] = f2b(acc[tm][tn][r]);
                }
            }
        }
    }
}

// -------------------------------------------------------------------------
// Scores (unchanged R11/R12).
template <int K>
__global__ __launch_bounds__(256) void score_k(const bf16* __restrict__ X,
                                               const bf16* __restrict__ Wab,
                                               float* __restrict__ ss,
                                               float* __restrict__ st)
{
    constexpr int VPL = K / 64;
    const int wave = threadIdx.x >> 6, lane = threadIdx.x & 63;
    const int n = blockIdx.x * 4 + wave;
    const int b = n >> 10, nn = n & 1023;

    const bf16* xr = X + (size_t)n * K + lane * VPL;
    float xv[VPL];
    if (VPL == 4) {
        short4v v = *(const short4v*)xr;
        #pragma unroll
        for (int t = 0; t < 4; t++) xv[t] = s2f(v[t]);
    } else {
        #pragma unroll
        for (int c = 0; c < VPL / 8; c++) {
            bhalf8 v = *(const bhalf8*)(xr + c * 8);
            #pragma unroll
            for (int t = 0; t < 8; t++) xv[c * 8 + t] = s2f(v[t]);
        }
    }

    #pragma unroll
    for (int hh = 0; hh < 16; hh++) {
        const bf16* wr = Wab + (size_t)hh * K + lane * VPL;
        float acc = 0.f;
        if (VPL == 4) {
            short4v v = *(const short4v*)wr;
            #pragma unroll
            for (int t = 0; t < 4; t++) acc = fmaf(xv[t], s2f(v[t]), acc);
        } else {
            #pragma unroll
            for (int c = 0; c < VPL / 8; c++) {
                bhalf8 v = *(const bhalf8*)(wr + c * 8);
                #pragma unroll
                for (int t = 0; t < 8; t++) acc = fmaf(xv[c * 8 + t], s2f(v[t]), acc);
            }
        }
        #pragma unroll
        for (int off = 32; off; off >>= 1) acc += __shfl_down(acc, off, 64);
        if (lane == 0) {
            const int h = hh & 7;
            if (hh < 8) ss[(b * 8 + h) * 1024 + nn] = acc;
            else        st[(b * 8 + h) * 1024 + nn] = acc;
        }
    }
}

// -------------------------------------------------------------------------
// Fused layer-1 attention v4: R12 structure + DEPTH-2 mask register prefetch
// (mv0/mv1 rotation) so mask HBM-miss latency (~900cy) is covered by ~2 iters.
__global__ __launch_bounds__(256) void attn_fused(const float* __restrict__ s_src_t,
                                                  const float* __restrict__ s_tgt_t,
                                                  const bf16* __restrict__ maskb,
                                                  const bf16* __restrict__ pT,
                                                  const bf16* __restrict__ sk,
                                                  const void* __restrict__ bias,
                                                  bf16* __restrict__ x2,
                                                  const int* __restrict__ flag)
{
    __shared__ __align__(16) short sA[2][32][32];    // exp numerators
    __shared__ __align__(16) short sB[2][256][32];   // pT tile (f x k)
    __shared__ short sStgt[1024];                    // s_tgt (bf16)
    __shared__ float sInvl[32];

    const int tid = threadIdx.x;
    const int by = blockIdx.x, bh = blockIdx.y;
    const int b = bh >> 3, h = bh & 7;
    const int f32 = *flag;
    const int wave = tid >> 6, lane = tid & 63;
    const int lrow = lane & 15, quad = lane >> 4;

    #pragma unroll
    for (int q = 0; q < 4; q++)
        sStgt[q * 256 + tid] = f2s(s_tgt_t[bh * 1024 + q * 256 + tid]);

    const int row  = tid >> 3;            // 0..31
    const int col0 = (tid & 7) * 4;       // 0..28
    const float ssr = s_src_t[bh * 1024 + by * 32 + row];
    const size_t mrow0 = ((size_t)(b * 1024 + by * 32 + row)) << 10;

    const bf16* gB = pT + ((size_t)bh << 18) + (size_t)(tid >> 2) * 1024 + (tid & 3) * 8;

    floatx4 acc[2][4];
    #pragma unroll
    for (int i = 0; i < 2; i++)
        #pragma unroll
        for (int j = 0; j < 4; j++)
            acc[i][j] = (floatx4){0.f, 0.f, 0.f, 0.f};

    float lacc = 0.f;

    auto stageB = [&](int k0, int buf) {
        const bf16* g = gB + k0;
        char* l = (char*)&sB[buf][0][0] + tid * 16;
        #pragma unroll
        for (int c = 0; c < 4; c++)
            gl_lds16(g + (size_t)(64 * c) * 1024, l + c * 4096);
    };
    auto genA = [&](int k0, int buf, const float* mv) {
        const short* sp = &sStgt[k0 + col0];
        short4v ev;
        #pragma unroll
        for (int t = 0; t < 4; t++) {
            float x = ssr + s2f(sp[t]);
            x = fmaxf(x, 0.2f * x);          // leaky_relu(0.2)
            float e = __expf(x + mv[t]);
            lacc += e;
            ev[t] = f2s(e);
        }
        *(short4v*)&sA[buf][row][col0] = ev;
    };

    float mv0[4], mv1[4];
    stageB(0, 0);
    load_mask4b(maskb, mrow0 + col0, mv0);            // tile 0
    __syncthreads();
    genA(0, 0, mv0);                                  // consume tile 0
    load_mask4b(maskb, mrow0 + 32 + col0, mv0);       // tile 1 (next consumed)
    load_mask4b(maskb, mrow0 + 64 + col0, mv1);       // tile 2 (depth-2)

    int cur = 0;
    for (int k0 = 0; k0 < 1024; k0 += 32, cur ^= 1) {
        __syncthreads();
        if (k0 + 32 < 1024) {
            const int nxt = cur ^ 1;
            stageB(k0 + 32, nxt);
            genA(k0 + 32, nxt, mv0);                  // tile k0/32+1
            #pragma unroll
            for (int t = 0; t < 4; t++) mv0[t] = mv1[t];
            if (k0 + 96 < 1024)
                load_mask4b(maskb, mrow0 + k0 + 96 + col0, mv1);
        }
        bhalf8 af[2], bfr[4];
        #pragma unroll
        for (int mt = 0; mt < 2; mt++)
            af[mt] = *(const bhalf8*)&sA[cur][mt * 16 + lrow][quad * 8];
        #pragma unroll
        for (int nt = 0; nt < 4; nt++)
            bfr[nt] = *(const bhalf8*)&sB[cur][wave * 64 + nt * 16 + lrow][quad * 8];
        #pragma unroll
        for (int mt = 0; mt < 2; mt++)
            #pragma unroll
            for (int nt = 0; nt < 4; nt++)
                acc[mt][nt] = __builtin_amdgcn_mfma_f32_16x16x32_bf16(af[mt], bfr[nt], acc[mt][nt], 0, 0, 0);
    }

    lacc += __shfl_xor(lacc, 1, 64);
    lacc += __shfl_xor(lacc, 2, 64);
    lacc += __shfl_xor(lacc, 4, 64);
    if ((tid & 7) == 0) sInvl[row] = 1.0f / lacc;
    __syncthreads();

    #pragma unroll
    for (int mt = 0; mt < 2; mt++) {
        #pragma unroll
        for (int r = 0; r < 4; r++) {
            const int rl = mt * 16 + quad * 4 + r;
            const int rg = by * 32 + rl;
            const float il = sInvl[rl];
            #pragma unroll
            for (int nt = 0; nt < 4; nt++) {
                const int col = wave * 64 + nt * 16 + lrow;
                const int hf = h * 256 + col;
                const size_t idx = ((size_t)(b * 1024 + rg)) * 2048 + hf;
                float v = acc[mt][nt][r] * il + b2f(sk[idx]) + loadf(bias, hf, f32);
                v = (v > 0.f) ? v : expm1f(v);     // ELU
                x2[idx] = f2b(v);
            }
        }
    }
}

// -------------------------------------------------------------------------
// Fused layer-2 denominators + weighted column sums. 32-row chunks,
// grid (32 bh, 32 iz) = 1024 blocks (4/CU).
__global__ __launch_bounds__(256) void colsoft_k(const float* __restrict__ s_src_t,
                                                 const float* __restrict__ s_tgt_t,
                                                 const bf16* __restrict__ maskb,
                                                 float* __restrict__ c)
{
    __shared__ float sS[32];
    __shared__ float sIl[32];
    const int bh = blockIdx.x, iz = blockIdx.y, b = bh >> 3;
    const int tid = threadIdx.x;
    const int i0 = iz * 32;
    if (tid < 32) sS[tid] = s_src_t[bh * 1024 + i0 + tid];
    __syncthreads();

    // ---- pass 1: row denominators (8 threads/row, 128 j each) ----
    {
        const int row = tid >> 3, c8 = tid & 7;
        const float ssr = sS[row];
        const size_t mrow = ((size_t)(b * 1024 + i0 + row)) << 10;
        float l = 0.f;
        #pragma unroll 4
        for (int q = 0; q < 32; q++) {
            const int j = c8 * 128 + q * 4;
            float mv[4];
            load_mask4b(maskb, mrow + j, mv);
            float4 s4 = *(const float4*)(s_tgt_t + bh * 1024 + j);
            float sv[4] = {s4.x, s4.y, s4.z, s4.w};
            #pragma unroll
            for (int t = 0; t < 4; t++) {
                float x = ssr + sv[t];
                x = fmaxf(x, 0.2f * x);
                l += __expf(x + mv[t]);
            }
        }
        l += __shfl_xor(l, 1, 64);
        l += __shfl_xor(l, 2, 64);
        l += __shfl_xor(l, 4, 64);
        if ((tid & 7) == 0) sIl[row] = 1.0f / l;
    }
    __syncthreads();

    // ---- pass 2: column partial sums (thread = 4 cols, loop 32 rows) ----
    const int j0 = tid * 4;
    float4 s4 = *(const float4*)(s_tgt_t + bh * 1024 + j0);
    float sv[4] = {s4.x, s4.y, s4.z, s4.w};
    float a[4] = {0.f, 0.f, 0.f, 0.f};
    #pragma unroll 4
    for (int r = 0; r < 32; r++) {
        const float sr = sS[r], il = sIl[r];
        float mv[4];
        load_mask4b(maskb, (((size_t)(b * 1024 + i0 + r)) << 10) + j0, mv);
        #pragma unroll
        for (int t = 0; t < 4; t++) {
            float x = sr + sv[t];
            x = fmaxf(x, 0.2f * x);
            a[t] = fmaf(il, __expf(x + mv[t]), a[t]);
        }
    }
    #pragma unroll
    for (int t = 0; t < 4; t++)
        atomicAdd(&c[bh * 1024 + j0 + t], a[t]);
}

// -------------------------------------------------------------------------
// y[bh][k] += sum_{j in 32-chunk} c[bh,j]*x2[b,j,k]; xbar += rowsum (unchanged).
__global__ __launch_bounds__(256) void yx_k(const bf16* __restrict__ x2,
                                            const float* __restrict__ c,
                                            float* __restrict__ y,
                                            float* __restrict__ xbar)
{
    __shared__ float sC[8][32];
    const int b = blockIdx.x, kt = blockIdx.y, jc = blockIdx.z;
    const int t = threadIdx.x;
    const int k = kt * 256 + t;
    const int j0 = jc * 32;
    {
        const int h = t >> 5, jj = t & 31;
        sC[h][jj] = c[(b * 8 + h) * 1024 + j0 + jj];
    }
    __syncthreads();
    float acc[8] = {0.f, 0.f, 0.f, 0.f, 0.f, 0.f, 0.f, 0.f};
    float ax = 0.f;
    #pragma unroll 4
    for (int jj = 0; jj < 32; jj++) {
        const float xv = b2f(x2[((size_t)(b * 1024 + j0 + jj)) * 2048 + k]);
        ax += xv;
        #pragma unroll
        for (int h = 0; h < 8; h++) acc[h] = fmaf(sC[h][jj], xv, acc[h]);
    }
    #pragma unroll
    for (int h = 0; h < 8; h++)
        atomicAdd(&y[(b * 8 + h) * 2048 + k], acc[h]);
    atomicAdd(&xbar[b * 2048 + k], ax);
}

// -------------------------------------------------------------------------
// Fused gamat (blocks [0,1024)) + skipvec (blocks [1024,2048)).
// Block covers ALL 4 batches (W2/skip2 read exactly once) in 16-k chunks:
// grid portion (8 h x 128 kc) each.
__global__ __launch_bounds__(256) void gs_k(const void* __restrict__ W2,
                                            const void* __restrict__ skip2,
                                            const float* __restrict__ y,
                                            const float* __restrict__ xbar,
                                            float* __restrict__ gA,
                                            float* __restrict__ gS,
                                            const int* __restrict__ flagp)
{
    __shared__ float sV[4][16];
    const int f32 = *flagp;
    int id = blockIdx.x;
    const int gam = (id < 1024) ? 1 : 0;
    if (!gam) id -= 1024;
    const int h = id & 7, kc = id >> 3;        // h(8) x kc(128)
    const int k0 = kc * 16, f = threadIdx.x;
    if (threadIdx.x < 64) {
        const int bb = threadIdx.x >> 4, kk = threadIdx.x & 15;
        sV[bb][kk] = gam ? y[(bb * 8 + h) * 2048 + k0 + kk]
                         : xbar[bb * 2048 + k0 + kk];
    }
    __syncthreads();
    const void* W = gam ? W2 : skip2;
    float acc[4] = {0.f, 0.f, 0.f, 0.f};
    #pragma unroll 4
    for (int kk = 0; kk < 16; kk++) {
        const float w = loadf(W, (size_t)(k0 + kk) * 2048 + h * 256 + f, f32);
        #pragma unroll
        for (int bb = 0; bb < 4; bb++) acc[bb] = fmaf(sV[bb][kk], w, acc[bb]);
    }
    if (gam) {
        #pragma unroll
        for (int bb = 0; bb < 4; bb++)
            atomicAdd(&gA[(bb * 8 + h) * 256 + f], acc[bb]);
    } else {
        #pragma unroll
        for (int bb = 0; bb < 4; bb++)
            atomicAdd(&gS[bb * 2048 + h * 256 + f], acc[bb]);
    }
}

// -------------------------------------------------------------------------
// classify (unchanged)
__global__ __launch_bounds__(256) void classify2_k(const float* __restrict__ gA,
                                                   const float* __restrict__ gS,
                                                   const void* __restrict__ b2,
                                                   const void* __restrict__ Wc,
                                                   const void* __restrict__ bc,
                                                   void* __restrict__ out,
                                                   const int* __restrict__ flag)
{
    __shared__ float gv[256];
    const int f32 = *flag;
    const int b = blockIdx.x, f = threadIdx.x;
    float s = 0.f;
    #pragma unroll
    for (int h = 0; h < 8; h++)
        s += gA[(b * 8 + h) * 256 + f] + gS[b * 2048 + h * 256 + f];
    gv[f] = s * (1.0f / 8192.0f) + loadf(b2, f, f32);
    __syncthreads();
    if (f < 10) {
        float acc = loadf(bc, f, f32);
        for (int k = 0; k < 256; k++)
            acc = fmaf(gv[k], loadf(Wc, k * 10 + f, f32), acc);
        if (f32) ((float*)out)[b * 10 + f] = acc;
        else     ((bf16*)out)[b * 10 + f] = f2b(acc);
    }
}

// -------------------------------------------------------------------------
extern "C" void kernel_launch(void* const* d_in, const int* in_sizes, int n_in,
                              void* d_out, int out_size, void* d_ws, size_t ws_size,
                              hipStream_t stream)
{
    (void)in_sizes; (void)n_in; (void)out_size; (void)ws_size;
    const void* feat   = d_in[0];
    const void* mask   = d_in[2];
    const void* W1     = d_in[3];
    const void* a_src1 = d_in[4];
    const void* a_tgt1 = d_in[5];
    const void* skip1  = d_in[6];
    const void* b1     = d_in[7];
    const void* W2     = d_in[8];
    const void* a_src2 = d_in[9];
    const void* a_tgt2 = d_in[10];
    const void* skip2  = d_in[11];
    const void* b2v    = d_in[12];
    const void* Wc     = d_in[13];
    const void* bc     = d_in[14];

    char* ws = (char*)d_ws;
    size_t off = 0;
    auto alloc = [&](size_t bytes) -> void* {
        void* p = ws + off;
        off += (bytes + 255) & ~(size_t)255;
        return p;
    };
    int*   flag  = (int*)alloc(256);
    bf16*  featc = (bf16*)alloc(4096ull * 256 * 2);
    bf16*  maskb = (bf16*)alloc(4ull * 1024 * 1024 * 2);
    bf16*  W1t   = (bf16*)alloc(2048ull * 256 * 2);
    bf16*  S1t   = (bf16*)alloc(2048ull * 256 * 2);
    bf16*  sk1   = (bf16*)alloc(4096ull * 2048 * 2);
    bf16*  x2    = (bf16*)alloc(4096ull * 2048 * 2);
    bf16*  pT    = (bf16*)alloc(4096ull * 2048 * 2);
    float* ss    = (float*)alloc(32ull * 1024 * 4);
    float* st    = (float*)alloc(32ull * 1024 * 4);
    bf16*  Wa1b  = (bf16*)alloc(16ull * 256 * 2);
    bf16*  Wa2b  = (bf16*)alloc(16ull * 2048 * 2);
    // cbuf, gA, gS, xbar, y contiguous: zeroed in prep_k
    float* cbuf = (float*)alloc(32ull * 1024 * 4);     // 32768 floats
    float* gA   = (float*)alloc(32ull * 256 * 4);      // 8192
    float* gS   = (float*)alloc(4ull * 2048 * 4);      // 8192
    float* xbar = (float*)alloc(4ull * 2048 * 4);      // 8192
    float* y    = (float*)alloc(32ull * 2048 * 4);     // 65536
    const int nzero = 32768 + 3 * 8192 + 65536;        // 122880

    // 1. fused prep
    prep_k<<<10272, 256, 0, stream>>>(feat, featc, mask, maskb, cbuf, nzero,
                                      W1, W1t, skip1, S1t, W2,
                                      a_src1, a_tgt1, a_src2, a_tgt2,
                                      Wa1b, Wa2b, flag);
    // 2. dual GEMM: pT (direct transposed layout) + sk1
    gemm_dual<<<dim3(32, 16, 2), 256, 0, stream>>>(featc, W1t, S1t, pT, sk1);
    // 3. layer-1 scores
    score_k<256><<<1024, 256, 0, stream>>>(featc, Wa1b, ss, st);
    // 4. fused layer-1 attention (depth-2 mask prefetch)
    attn_fused<<<dim3(32, 32), 256, 0, stream>>>(ss, st, maskb, pT, sk1, b1, x2, flag);
    // 5. layer-2 scores
    score_k<2048><<<1024, 256, 0, stream>>>(x2, Wa2b, ss, st);
    // 6. fused softmax denominators + column sums (1024 blocks)
    colsoft_k<<<dim3(32, 32), 256, 0, stream>>>(ss, st, maskb, cbuf);
    // 7. weighted + plain row aggregation of x2
    yx_k<<<dim3(4, 8, 32), 256, 0, stream>>>(x2, cbuf, y, xbar);
    // 8. fused gamat + skipvec (W2/skip2 read once)
    gs_k<<<2048, 256, 0, stream>>>(W2, skip2, y, xbar, gA, gS, flag);
    // 9. classify
    classify2_k<<<4, 256, 0, stream>>>(gA, gS, b2v, Wc, bc, d_out, flag);
}